// Round 1
// baseline (428.735 us; speedup 1.0000x reference)
//
#include <hip/hip_runtime.h>

#define HID      64
#define HEADS    8
#define MOL_N    40
#define PRO_N    400
#define NGRAPH   256
#define NTHREADS 1024

typedef float vfloat4 __attribute__((ext_vector_type(4)));

__device__ __forceinline__ float elu_plus(float x, float c) {
    // elu(x) + c, alpha=1
    return x > 0.0f ? x + c : __expf(x) - 1.0f + c;
}

// ---------------------------------------------------------------------------
// Fully fused kernel: one block per complex (grid = 256 = #CUs, 1024 thr).
//   Phase A: project this complex's 40 mol rows + 400 pro rows into LDS
//            (pro = pro_feats * spatial; biases folded into the mol side).
//   Phase B: emit all 40*400 edges: mu/sg = elu(pro + mol) + c, plain
//            coalesced dwordx4 streaming stores (262 MB total across grid);
//            accumulate mu per head in registers.
//   Phase C: butterfly + LDS reduce -> y[b] -> per-graph MLP head -> y_pred.
// No workspace, no atomics, no inter-kernel global round trip.
// LDS = 2*4KB weights + 2*12.8KB pro tables + 2*1.28KB mol tables ~ 37 KB.
// ---------------------------------------------------------------------------
__global__ __launch_bounds__(NTHREADS) void fused_kernel(
    const float* __restrict__ mol_feats, const float* __restrict__ pro_feats,
    const float* __restrict__ spatial,   const float* __restrict__ sigma_w,
    const float* __restrict__ sigma_b,   const float* __restrict__ mu_w,
    const float* __restrict__ mu_b,
    const float* __restrict__ w1,        const float* __restrict__ b1,
    const float* __restrict__ w2,        const float* __restrict__ b2,
    float* __restrict__ mu_out, float* __restrict__ sg_out,
    float* __restrict__ y_pred)
{
    const int b   = (int)blockIdx.x;
    const int tid = (int)threadIdx.x;

    __shared__ float   wsig[2 * HID * HEADS];   // flat copy of sigma_w  (4 KB)
    __shared__ float   wmu [2 * HID * HEADS];   // flat copy of mu_w     (4 KB)
    __shared__ vfloat4 proS[PRO_N][2];          // [j][q]: sigma proj, heads q*4..q*4+3
    __shared__ vfloat4 proM[PRO_N][2];          // [j][q]: mu proj
    __shared__ vfloat4 molS[MOL_N][2];          // bias folded
    __shared__ vfloat4 molM[MOL_N][2];
    __shared__ float   ysum[16][HEADS];         // per-wave mu partials
    __shared__ float   yv[HEADS];

    // stage weights: 2*64*8 == 1024 == NTHREADS, one element per thread
    wsig[tid] = sigma_w[tid];
    wmu [tid] = mu_w  [tid];
    __syncthreads();

    // ---------------- Phase A: projections into LDS ----------------
    // pro side: 400*8 = 3200 (row, head) tasks. 8 lanes share a row ->
    // identical load addresses coalesce to a broadcast; LDS weight reads are
    // 8 consecutive floats x 8-way broadcast (conflict-free).
    for (int task = tid; task < PRO_N * HEADS; task += NTHREADS) {
        const int r = task >> 3, h = task & 7;
        const vfloat4* pf = (const vfloat4*)pro_feats + ((size_t)b * PRO_N + r) * (HID / 4);
        const vfloat4* sf = (const vfloat4*)spatial   + ((size_t)b * PRO_N + r) * (HID / 4);
        float as0 = 0.f, as1 = 0.f, am0 = 0.f, am1 = 0.f;   // 2 partials: break dep chain
#pragma unroll
        for (int k4 = 0; k4 < HID / 4; ++k4) {
            vfloat4 a = pf[k4], s = sf[k4];
            const float x0 = a.x * s.x, x1 = a.y * s.y, x2 = a.z * s.z, x3 = a.w * s.w;
            const float* wg = &wsig[(HID + k4 * 4) * HEADS + h];   // pro rows of W
            const float* wm = &wmu [(HID + k4 * 4) * HEADS + h];
            as0 += x0 * wg[0];  as1 += x1 * wg[8];
            as0 += x2 * wg[16]; as1 += x3 * wg[24];
            am0 += x0 * wm[0];  am1 += x1 * wm[8];
            am0 += x2 * wm[16]; am1 += x3 * wm[24];
        }
        ((float*)proS)[r * 8 + h] = as0 + as1;
        ((float*)proM)[r * 8 + h] = am0 + am1;
    }
    // mol side: 40*8 = 320 tasks, biases folded here
    if (tid < MOL_N * HEADS) {
        const int r = tid >> 3, h = tid & 7;
        const vfloat4* mf = (const vfloat4*)mol_feats + ((size_t)b * MOL_N + r) * (HID / 4);
        float as0 = sigma_b[h], as1 = 0.f, am0 = mu_b[h], am1 = 0.f;
#pragma unroll
        for (int k4 = 0; k4 < HID / 4; ++k4) {
            vfloat4 a = mf[k4];
            const float* wg = &wsig[(k4 * 4) * HEADS + h];         // mol rows of W
            const float* wm = &wmu [(k4 * 4) * HEADS + h];
            as0 += a.x * wg[0];  as1 += a.y * wg[8];
            as0 += a.z * wg[16]; as1 += a.w * wg[24];
            am0 += a.x * wm[0];  am1 += a.y * wm[8];
            am0 += a.z * wm[16]; am1 += a.w * wm[24];
        }
        ((float*)molS)[r * 8 + h] = as0 + as1;
        ((float*)molM)[r * 8 + h] = am0 + am1;
    }
    __syncthreads();

    // ---------------- Phase B: edge map + mu accumulation ----------------
    // thread (q = tid&1, jj = tid>>1) owns pro residue jj, head-half q.
    // Per-complex float layout: ((r*400 + j)*8 + q*4 + k); chunk index
    // t = r*800 + tid  -> stores are perfectly sequential across the block.
    const int q  = tid & 1;
    const int jj = tid >> 1;
    float acc0 = 0.f, acc1 = 0.f, acc2 = 0.f, acc3 = 0.f;
    if (tid < 2 * PRO_N) {
        const vfloat4 pm = proM[jj][q];          // hoisted: fixed per thread
        const vfloat4 ps = proS[jj][q];
        vfloat4* mu4 = (vfloat4*)mu_out + (size_t)b * (MOL_N * PRO_N * 2);
        vfloat4* sg4 = (vfloat4*)sg_out + (size_t)b * (MOL_N * PRO_N * 2);
        for (int r = 0; r < MOL_N; ++r) {
            const vfloat4 mm = molM[r][q];       // 2 addrs/wave -> broadcast
            const vfloat4 ms = molS[r][q];
            vfloat4 vmu, vsg;
            vmu.x = elu_plus(pm.x + mm.x, 1.0f);
            vmu.y = elu_plus(pm.y + mm.y, 1.0f);
            vmu.z = elu_plus(pm.z + mm.z, 1.0f);
            vmu.w = elu_plus(pm.w + mm.w, 1.0f);
            vsg.x = elu_plus(ps.x + ms.x, 1.1f);
            vsg.y = elu_plus(ps.y + ms.y, 1.1f);
            vsg.z = elu_plus(ps.z + ms.z, 1.1f);
            vsg.w = elu_plus(ps.w + ms.w, 1.1f);
            const int t = r * (2 * PRO_N) + tid;
            mu4[t] = vmu;                        // plain streaming stores
            sg4[t] = vsg;
            acc0 += vmu.x; acc1 += vmu.y; acc2 += vmu.z; acc3 += vmu.w;
        }
    }

    // butterfly over lanes of equal parity (masks 2..32 preserve bit 0):
    // afterwards lane0 holds heads 0-3 sum, lane1 holds heads 4-7 sum.
    // Threads >= 800 participate with acc == 0 (keeps wave 12 well-defined).
#pragma unroll
    for (int mask = 2; mask < 64; mask <<= 1) {
        acc0 += __shfl_xor(acc0, mask, 64);
        acc1 += __shfl_xor(acc1, mask, 64);
        acc2 += __shfl_xor(acc2, mask, 64);
        acc3 += __shfl_xor(acc3, mask, 64);
    }
    const int wv = tid >> 6, lane = tid & 63;
    if (lane < 2) {
        ysum[wv][lane * 4 + 0] = acc0;
        ysum[wv][lane * 4 + 1] = acc1;
        ysum[wv][lane * 4 + 2] = acc2;
        ysum[wv][lane * 4 + 3] = acc3;
    }
    __syncthreads();

    if (tid < HEADS) {
        float s = 0.f;
#pragma unroll
        for (int i = 0; i < 16; ++i) s += ysum[i][tid];
        yv[tid] = s * 0.001f;
    }
    __syncthreads();

    // ---------------- Phase C: per-graph MLP head (wave 0 only) -----------
    if (tid < 64) {
        float contrib = 0.f;
        if (tid < 2 * HEADS) {
            float a = b1[tid];
#pragma unroll
            for (int h = 0; h < HEADS; ++h) a += yv[h] * w1[h * (2 * HEADS) + tid];
            a = a > 0.f ? a : __expf(a) - 1.f;   // elu
            contrib = a * w2[tid];
        }
        // lanes 16-63 carry 0; tree-add down to lane 0
        contrib += __shfl_down(contrib, 8, 64);
        contrib += __shfl_down(contrib, 4, 64);
        contrib += __shfl_down(contrib, 2, 64);
        contrib += __shfl_down(contrib, 1, 64);
        if (tid == 0) y_pred[b] = contrib + b2[0];
    }
}

extern "C" void kernel_launch(void* const* d_in, const int* in_sizes, int n_in,
                              void* d_out, int out_size, void* d_ws, size_t ws_size,
                              hipStream_t stream) {
    const float* mol_feats = (const float*)d_in[0];
    const float* pro_feats = (const float*)d_in[1];
    const float* spatial   = (const float*)d_in[2];
    const float* sigma_w   = (const float*)d_in[3];
    const float* sigma_b   = (const float*)d_in[4];
    const float* mu_w      = (const float*)d_in[5];
    const float* mu_b      = (const float*)d_in[6];
    const float* w1        = (const float*)d_in[7];
    const float* b1        = (const float*)d_in[8];
    const float* w2        = (const float*)d_in[9];
    const float* b2        = (const float*)d_in[10];

    const int E = in_sizes[11];         // 4,096,000 (mol_index length)

    float* mu_out = (float*)d_out;
    float* sg_out = mu_out + (size_t)E * HEADS;
    float* y_pred = sg_out + (size_t)E * HEADS;

    fused_kernel<<<NGRAPH, NTHREADS, 0, stream>>>(
        mol_feats, pro_feats, spatial, sigma_w, sigma_b, mu_w, mu_b,
        w1, b1, w2, b2, mu_out, sg_out, y_pred);
}

// Round 2
// 356.874 us; speedup vs baseline: 1.2014x; 1.2014x over previous
//
#include <hip/hip_runtime.h>

#define HID    64
#define HEADS  8
#define MOL_N  40
#define PRO_N  400
#define NGRAPH 256

typedef float vfloat4 __attribute__((ext_vector_type(4)));

__device__ __forceinline__ float elu_plus(float x, float c) {
    // elu(x) + c, alpha=1
    return x > 0.0f ? x + c : __expf(x) - 1.0f + c;
}

// ---------------------------------------------------------------------------
// Kernel 1: per-node projections (unchanged from R1 — measured fine).
//   mol side: mol_s[m,h] = mol_feats[m,:] @ sigma_w[:64,h] + sigma_b[h]
//             mol_m[m,h] = mol_feats[m,:] @ mu_w[:64,h]    + mu_b[h]
//   pro side: pro = pro_feats * spatial
//             pro_s[p,h] = pro @ sigma_w[64:,h];  pro_m[p,h] = pro @ mu_w[64:,h]
// One block = 32 rows, 256 threads (8 threads/row = one (row,head) each).
// Block 0 additionally zeroes the per-graph accumulator.
// ---------------------------------------------------------------------------
__global__ __launch_bounds__(256) void proj_kernel(
    const float* __restrict__ mol_feats, const float* __restrict__ pro_feats,
    const float* __restrict__ spatial,   const float* __restrict__ sigma_w,
    const float* __restrict__ sigma_b,   const float* __restrict__ mu_w,
    const float* __restrict__ mu_b,
    float* __restrict__ mol_s, float* __restrict__ mol_m,
    float* __restrict__ pro_s, float* __restrict__ pro_m,
    float* __restrict__ y_acc, int mol_blocks)
{
    __shared__ float rows[32][HID + 1];     // +1 pad: breaks 32-bank aliasing
    __shared__ float wsig[HID][HEADS];
    __shared__ float wmu [HID][HEADS];

    const int tid = threadIdx.x;
    const bool is_mol = (int)blockIdx.x < mol_blocks;

    if (blockIdx.x == 0) {
        for (int i = tid; i < NGRAPH * HEADS; i += 256) y_acc[i] = 0.0f;
    }

    // stage weights (mol: rows [0,64); pro: rows [64,128))
    const int wofs = is_mol ? 0 : HID * HEADS;
    for (int i = tid; i < HID * HEADS; i += 256) {
        wsig[i / HEADS][i % HEADS] = sigma_w[wofs + i];
        wmu [i / HEADS][i % HEADS] = mu_w  [wofs + i];
    }

    // stage 32 input rows (float4-vectorized, coalesced)
    const int r0 = (is_mol ? (int)blockIdx.x : ((int)blockIdx.x - mol_blocks)) * 32;
    if (is_mol) {
        const float4* src = (const float4*)mol_feats + (size_t)r0 * (HID / 4);
        for (int i = tid; i < 32 * (HID / 4); i += 256) {
            float4 v = src[i];
            int lr = i / (HID / 4), k4 = (i % (HID / 4)) * 4;
            rows[lr][k4 + 0] = v.x; rows[lr][k4 + 1] = v.y;
            rows[lr][k4 + 2] = v.z; rows[lr][k4 + 3] = v.w;
        }
    } else {
        const float4* srcp = (const float4*)pro_feats + (size_t)r0 * (HID / 4);
        const float4* srcs = (const float4*)spatial   + (size_t)r0 * (HID / 4);
        for (int i = tid; i < 32 * (HID / 4); i += 256) {
            float4 a = srcp[i];
            float4 b = srcs[i];
            int lr = i / (HID / 4), k4 = (i % (HID / 4)) * 4;
            rows[lr][k4 + 0] = a.x * b.x; rows[lr][k4 + 1] = a.y * b.y;
            rows[lr][k4 + 2] = a.z * b.z; rows[lr][k4 + 3] = a.w * b.w;
        }
    }
    __syncthreads();

    const int lr = tid >> 3;      // local row
    const int h  = tid & 7;       // head
    float as = 0.0f, am = 0.0f;
#pragma unroll
    for (int k = 0; k < HID; ++k) {
        float x = rows[lr][k];
        as += x * wsig[k][h];
        am += x * wmu [k][h];
    }
    const int gr = r0 + lr;
    if (is_mol) {
        mol_s[gr * HEADS + h] = as + sigma_b[h];   // fold biases into mol side
        mol_m[gr * HEADS + h] = am + mu_b[h];
    } else {
        pro_s[gr * HEADS + h] = as;
        pro_m[gr * HEADS + h] = am;
    }
}

// ---------------------------------------------------------------------------
// Kernel 2: edge map + mu segment-sum.  Grid = 256 complexes * 40 atoms,
// SWIZZLED: b = blockIdx & 255, r = blockIdx >> 8.  Round-robin XCD dispatch
// (xcd = blockIdx % 8) puts all 40 blocks of complex b on ONE XCD (b % 8),
// so its 51.2 KB projection table stays in that XCD's L2.
// Per-XCD working set: 32 complexes * 51.2 KB = 1.6 MB < 4 MB L2.
// R2 CHANGE (single variable vs the 354 µs baseline): plain stores instead
// of __builtin_nontemporal_store. NT-store throughput on gfx950 is
// unverified; the harness's own fillBuffer proves plain stores sustain
// ~6.5 TB/s. Worst-case downside is table re-fetch after L2 eviction
// (bounded ~+40 µs); upside if NT streams slowly is ~-100 µs.
// ---------------------------------------------------------------------------
__global__ __launch_bounds__(256) void edge_kernel(
    const float* __restrict__ mol_s, const float* __restrict__ mol_m,
    const float* __restrict__ pro_s, const float* __restrict__ pro_m,
    float* __restrict__ mu_out, float* __restrict__ sg_out,
    float* __restrict__ y_acc)
{
    const int bi  = blockIdx.x;
    const int b   = bi & (NGRAPH - 1);   // complex id
    const int r   = bi >> 8;             // atom within complex
    const int m   = b * MOL_N + r;       // global mol row
    const int tid = threadIdx.x;

    __shared__ float s_mol[16];    // [0:8) = mol_s row, [8:16) = mol_m row
    __shared__ float s_hsum[HEADS];
    if (tid < 8)       s_mol[tid] = mol_s[m * HEADS + tid];
    else if (tid < 16) s_mol[tid] = mol_m[m * HEADS + (tid - 8)];
    if (tid < HEADS)   s_hsum[tid] = 0.0f;
    __syncthreads();

    const int q = tid & 1;         // head half: heads q*4 .. q*4+3
    float ms[4], mm[4];
#pragma unroll
    for (int k = 0; k < 4; ++k) {
        ms[k] = s_mol[q * 4 + k];
        mm[k] = s_mol[8 + q * 4 + k];
    }

    const vfloat4* pm4 = (const vfloat4*)pro_m + (size_t)b * PRO_N * 2;
    const vfloat4* ps4 = (const vfloat4*)pro_s + (size_t)b * PRO_N * 2;
    vfloat4* mu4 = (vfloat4*)mu_out + (size_t)m * PRO_N * 2;
    vfloat4* sg4 = (vfloat4*)sg_out + (size_t)m * PRO_N * 2;

    float acc[4] = {0.f, 0.f, 0.f, 0.f};
    for (int t = tid; t < PRO_N * 2; t += 256) {   // t = j*2 + q, q constant/thread
        vfloat4 pmv = pm4[t];
        vfloat4 psv = ps4[t];
        vfloat4 vmu, vsg;
        vmu.x = elu_plus(pmv.x + mm[0], 1.0f);
        vmu.y = elu_plus(pmv.y + mm[1], 1.0f);
        vmu.z = elu_plus(pmv.z + mm[2], 1.0f);
        vmu.w = elu_plus(pmv.w + mm[3], 1.0f);
        vsg.x = elu_plus(psv.x + ms[0], 1.1f);
        vsg.y = elu_plus(psv.y + ms[1], 1.1f);
        vsg.z = elu_plus(psv.z + ms[2], 1.1f);
        vsg.w = elu_plus(psv.w + ms[3], 1.1f);
        mu4[t] = vmu;              // R2: plain stores (was nontemporal)
        sg4[t] = vsg;
        acc[0] += vmu.x; acc[1] += vmu.y; acc[2] += vmu.z; acc[3] += vmu.w;
    }

    // reduce mu partials: butterfly over lanes of same parity (masks 2..32)
#pragma unroll
    for (int mask = 2; mask < 64; mask <<= 1) {
#pragma unroll
        for (int k = 0; k < 4; ++k) acc[k] += __shfl_xor(acc[k], mask, 64);
    }
    if ((tid & 63) < 2) {          // lane 0 (heads 0-3) and lane 1 (heads 4-7)
#pragma unroll
        for (int k = 0; k < 4; ++k) atomicAdd(&s_hsum[q * 4 + k], acc[k]);
    }
    __syncthreads();
    if (tid < HEADS) atomicAdd(&y_acc[b * HEADS + tid], s_hsum[tid]);
}

// ---------------------------------------------------------------------------
// Kernel 3: per-graph MLP head. One thread per graph.
//   y = elu(0.001 * y_acc @ w1 + b1);  y_pred = y @ w2 + b2
// ---------------------------------------------------------------------------
__global__ __launch_bounds__(256) void head_kernel(
    const float* __restrict__ y_acc, const float* __restrict__ w1,
    const float* __restrict__ b1,    const float* __restrict__ w2,
    const float* __restrict__ b2,    float* __restrict__ y_pred)
{
    const int g = threadIdx.x;
    float y[HEADS];
#pragma unroll
    for (int h = 0; h < HEADS; ++h) y[h] = y_acc[g * HEADS + h] * 0.001f;
    float out = b2[0];
#pragma unroll
    for (int o = 0; o < 2 * HEADS; ++o) {
        float a = b1[o];
#pragma unroll
        for (int h = 0; h < HEADS; ++h) a += y[h] * w1[h * (2 * HEADS) + o];
        a = a > 0.0f ? a : __expf(a) - 1.0f;   // elu
        out += a * w2[o];
    }
    y_pred[g] = out;
}

extern "C" void kernel_launch(void* const* d_in, const int* in_sizes, int n_in,
                              void* d_out, int out_size, void* d_ws, size_t ws_size,
                              hipStream_t stream) {
    const float* mol_feats = (const float*)d_in[0];
    const float* pro_feats = (const float*)d_in[1];
    const float* spatial   = (const float*)d_in[2];
    const float* sigma_w   = (const float*)d_in[3];
    const float* sigma_b   = (const float*)d_in[4];
    const float* mu_w      = (const float*)d_in[5];
    const float* mu_b      = (const float*)d_in[6];
    const float* w1        = (const float*)d_in[7];
    const float* b1        = (const float*)d_in[8];
    const float* w2        = (const float*)d_in[9];
    const float* b2        = (const float*)d_in[10];

    const int M = in_sizes[0] / HID;    // 10240
    const int P = in_sizes[1] / HID;    // 102400
    const int E = in_sizes[11];         // 4,096,000 (mol_index length)

    // workspace layout (all float, 16B-aligned slices)
    float* ws    = (float*)d_ws;
    float* mol_s = ws;                         // M*8
    float* mol_m = mol_s + (size_t)M * HEADS;  // M*8
    float* pro_s = mol_m + (size_t)M * HEADS;  // P*8
    float* pro_m = pro_s + (size_t)P * HEADS;  // P*8
    float* y_acc = pro_m + (size_t)P * HEADS;  // NGRAPH*8

    float* mu_out = (float*)d_out;
    float* sg_out = mu_out + (size_t)E * HEADS;
    float* y_pred = sg_out + (size_t)E * HEADS;

    const int mol_blocks = M / 32;
    const int pro_blocks = P / 32;

    proj_kernel<<<mol_blocks + pro_blocks, 256, 0, stream>>>(
        mol_feats, pro_feats, spatial, sigma_w, sigma_b, mu_w, mu_b,
        mol_s, mol_m, pro_s, pro_m, y_acc, mol_blocks);

    edge_kernel<<<M, 256, 0, stream>>>(
        mol_s, mol_m, pro_s, pro_m, mu_out, sg_out, y_acc);

    head_kernel<<<1, 256, 0, stream>>>(y_acc, w1, b1, w2, b2, y_pred);
}